// Round 12
// baseline (802.157 us; speedup 1.0000x reference)
//
#include <hip/hip_runtime.h>

#define N_NODESC 50000
#define N_EDGESC 400000
#define N_GRAPHSC 128
#define IN_DIMC 768
#define HIDC 128
#define NCLSC 11
#define BN_EPSC 1e-5f
#define NREP 64
#define SCAN_NB ((N_NODESC + 255) / 256)

typedef __bf16 bf16_t;
typedef __bf16 bf16x2 __attribute__((ext_vector_type(2)));
typedef __bf16 bf16x8 __attribute__((ext_vector_type(8)));
typedef float f32x4 __attribute__((ext_vector_type(4)));

typedef __attribute__((address_space(1))) void glb_void;
typedef __attribute__((address_space(3))) void lds_void;

__device__ __forceinline__ void cp16(const void* g, void* l) {
    // async global->LDS, 16B/lane; LDS dst = wave-uniform base + lane*16
    __builtin_amdgcn_global_load_lds((glb_void*)g, (lds_void*)l, 16, 0, 0);
}

__device__ __forceinline__ f32x4 mfma_16x16x32_bf16(bf16x8 a, bf16x8 b, f32x4 c) {
    return __builtin_amdgcn_mfma_f32_16x16x32_bf16(a, b, c, 0, 0, 0);
}

// ================= layer-1 GEMM: A fp32 [M,768], B from L2 to registers =========
// Tile 128x128xBK32, grid (M/128, 2). A: depth-1 double-buffered cp16 (2x16 KB
// LDS = 32 KB total -> 5 blocks/CU). B (Wb1, 384 KB, L2-hot) loaded straight to
// VGPRs each iter. Per iter: B(it) reg loads -> fence -> cp16 A(it+1) ->
// s_waitcnt vmcnt(4) (drains A(it)+B(it), keeps A(it+1) in flight) -> barrier.
__global__ __launch_bounds__(256) void gemm1_kernel(const float* __restrict__ A,
                                                    const bf16_t* __restrict__ Wb,
                                                    bf16_t* __restrict__ Cl,
                                                    bf16_t* __restrict__ Cr,
                                                    int M)
{
    constexpr int KC  = IN_DIMC;
    constexpr int NK  = KC / 32;
    constexpr int ASZ = 16384;
    __shared__ __align__(16) unsigned char Asm[2 * ASZ];

    const int t    = threadIdx.x;
    const int m0   = blockIdx.x * 128;
    const int half = blockIdx.y;
    const int wid  = t >> 6;
    const int lane = t & 63;
    const int wm   = (wid >> 1) * 64;
    const int wn   = (wid & 1) * 64;
    const int l16  = lane & 15;
    const int quad = lane >> 4;

    // A async-loader sources (XOR swizzle folded into the global side)
    const char* aSrc[4]; int aDst[4];
#pragma unroll
    for (int s = 0; s < 4; s++) {
        int L = (s * 4 + wid) * 64 + lane;          // 16B-chunk slot
        int r = L >> 3;                             // 8 chunks per 128-B half-row
        int c = (L & 7) ^ (r & 7);
        int row = m0 + r; if (row > M - 1) row = M - 1;   // clamp; never stored
        aSrc[s] = (const char*)(A + (size_t)row * KC + c * 4);
        aDst[s] = (s * 4 + wid) * 1024;
    }
    // A fragment LDS offsets
    int aOff[4][2];
#pragma unroll
    for (int i = 0; i < 4; i++) {
        int ra = wm + i * 16 + l16;
        aOff[i][0] = ra * 128 + (((2 * quad)     ^ (ra & 7)) * 16);
        aOff[i][1] = ra * 128 + (((2 * quad + 1) ^ (ra & 7)) * 16);
    }
    // B register-load base pointers (per j), L2-hot
    const bf16_t* bB[4];
#pragma unroll
    for (int j = 0; j < 4; j++)
        bB[j] = Wb + (size_t)(half * 128 + wn + j * 16 + l16) * KC + quad * 8;

    // prologue: stage A0
#pragma unroll
    for (int s = 0; s < 4; s++) cp16(aSrc[s], Asm + aDst[s]);

    f32x4 acc[4][4] = {};

    for (int it = 0; it < NK; ++it) {
        bf16x8 bfr[4];
#pragma unroll
        for (int j = 0; j < 4; j++)
            bfr[j] = *(const bf16x8*)(bB[j] + it * 32);     // global->VGPR (L2)
        asm volatile("" ::: "memory");                      // pin B-loads before cp16s
        if (it + 1 < NK) {
            const size_t ka = (size_t)(it + 1) * 128;       // bytes along row
            const int nb = (it + 1) & 1;
#pragma unroll
            for (int s = 0; s < 4; s++) cp16(aSrc[s] + ka, Asm + nb * ASZ + aDst[s]);
            asm volatile("s_waitcnt vmcnt(4)" ::: "memory"); // A(it)+B(it) done
        } else {
            asm volatile("s_waitcnt vmcnt(0)" ::: "memory");
        }
        asm volatile("s_barrier" ::: "memory");

        const unsigned char* Ab = Asm + (it & 1) * ASZ;
        bf16x8 af[4];
#pragma unroll
        for (int i = 0; i < 4; i++) {
            float4 u0 = *(const float4*)(Ab + aOff[i][0]);
            float4 u1 = *(const float4*)(Ab + aOff[i][1]);
            af[i][0] = (bf16_t)u0.x; af[i][1] = (bf16_t)u0.y;
            af[i][2] = (bf16_t)u0.z; af[i][3] = (bf16_t)u0.w;
            af[i][4] = (bf16_t)u1.x; af[i][5] = (bf16_t)u1.y;
            af[i][6] = (bf16_t)u1.z; af[i][7] = (bf16_t)u1.w;
        }
#pragma unroll
        for (int i = 0; i < 4; i++)
#pragma unroll
            for (int j = 0; j < 4; j++)
                acc[i][j] = mfma_16x16x32_bf16(af[i], bfr[j], acc[i][j]);

        asm volatile("s_barrier" ::: "memory");   // protect buf reused next iter
    }

    bf16_t* C = half ? Cr : Cl;
#pragma unroll
    for (int i = 0; i < 4; i++) {
        int rowb = m0 + wm + i * 16 + quad * 4;
#pragma unroll
        for (int j = 0; j < 4; j++) {
            int colh = wn + j * 16 + l16;
#pragma unroll
            for (int rr = 0; rr < 4; rr++) {
                int row = rowb + rr;
                if (row < M) C[(size_t)row * HIDC + colh] = (bf16_t)acc[i][j][rr];
            }
        }
    }
}

// ===== layer-2/3 GEMM: A bf16 [M,128]; K=128 -> stage FULL panels once =========
// A panel 32 KB + B panel 32 KB + BN table 1 KB; one __syncthreads; 4 MFMA iters
// with no in-loop waits. BN finalize (stats replicas -> scale/shift) fused.
__global__ __launch_bounds__(256) void gemm23_kernel(const bf16_t* __restrict__ A,
                                                     const bf16_t* __restrict__ Wb,
                                                     const float* __restrict__ stats,
                                                     const float* __restrict__ g,
                                                     const float* __restrict__ be,
                                                     bf16_t* __restrict__ Cl,
                                                     bf16_t* __restrict__ Cr,
                                                     int M)
{
    constexpr int KC = HIDC;
    __shared__ __align__(16) unsigned char Asm[32768];
    __shared__ __align__(16) unsigned char Bsm[32768];
    __shared__ float scS[256];

    const int t    = threadIdx.x;
    const int m0   = blockIdx.x * 128;
    const int half = blockIdx.y;
    const int wid  = t >> 6;
    const int lane = t & 63;
    const int wm   = (wid >> 1) * 64;
    const int wn   = (wid & 1) * 64;
    const int l16  = lane & 15;
    const int quad = lane >> 4;

    // fused BN finalize -> LDS
    if (t < HIDC) {
        float sum = 0.f, sumsq = 0.f;
        for (int r = 0; r < NREP; r++) {
            sum   += stats[r * 256 + t];
            sumsq += stats[r * 256 + HIDC + t];
        }
        float invM = 1.0f / (float)M;
        float mean = sum * invM;
        float var  = sumsq * invM - mean * mean;
        float s = rsqrtf(var + BN_EPSC) * g[t];
        scS[t] = s;
        scS[HIDC + t] = be[t] - mean * s;
    }

    // stage both panels (16-chunk rows, swizzle ^(r&7) folded into global side)
#pragma unroll
    for (int s = 0; s < 8; s++) {
        int L = (s * 4 + wid) * 64 + lane;    // slot 0..2047
        int r = L >> 4;
        int c = (L & 15) ^ (r & 7);
        int row = m0 + r; if (row > M - 1) row = M - 1;
        cp16((const char*)(A + (size_t)row * KC) + c * 16, Asm + (size_t)L * 16);
        cp16((const char*)(Wb + (size_t)(half * 128 + r) * KC) + c * 16, Bsm + (size_t)L * 16);
    }
    __syncthreads();

    f32x4 acc[4][4] = {};

#pragma unroll
    for (int it = 0; it < KC / 32; ++it) {
        bf16x8 af[4], bfr[4];
        float4 s0 = *(const float4*)&scS[it * 32 + quad * 8];
        float4 s1 = *(const float4*)&scS[it * 32 + quad * 8 + 4];
        float4 h0 = *(const float4*)&scS[HIDC + it * 32 + quad * 8];
        float4 h1 = *(const float4*)&scS[HIDC + it * 32 + quad * 8 + 4];
        float ss[8] = {s0.x, s0.y, s0.z, s0.w, s1.x, s1.y, s1.z, s1.w};
        float hh[8] = {h0.x, h0.y, h0.z, h0.w, h1.x, h1.y, h1.z, h1.w};
#pragma unroll
        for (int i = 0; i < 4; i++) {
            int ra = wm + i * 16 + l16;
            bf16x8 raw = *(const bf16x8*)(Asm + ra * 256 + (((it * 4 + quad) ^ (ra & 7)) * 16));
#pragma unroll
            for (int e = 0; e < 8; e++)
                af[i][e] = (bf16_t)fmaxf(fmaf((float)raw[e], ss[e], hh[e]), 0.0f);
        }
#pragma unroll
        for (int j = 0; j < 4; j++) {
            int rb = wn + j * 16 + l16;
            bfr[j] = *(const bf16x8*)(Bsm + rb * 256 + (((it * 4 + quad) ^ (rb & 7)) * 16));
        }
#pragma unroll
        for (int i = 0; i < 4; i++)
#pragma unroll
            for (int j = 0; j < 4; j++)
                acc[i][j] = mfma_16x16x32_bf16(af[i], bfr[j], acc[i][j]);
    }

    bf16_t* C = half ? Cr : Cl;
#pragma unroll
    for (int i = 0; i < 4; i++) {
        int rowb = m0 + wm + i * 16 + quad * 4;
#pragma unroll
        for (int j = 0; j < 4; j++) {
            int colh = wn + j * 16 + l16;
#pragma unroll
            for (int rr = 0; rr < 4; rr++) {
                int row = rowb + rr;
                if (row < M) C[(size_t)row * HIDC + colh] = (bf16_t)acc[i][j][rr];
            }
        }
    }
}

// ---------- fused init: weight converts + zero degi/stats ----------
__global__ void init_kernel(const float* __restrict__ W1l, const float* __restrict__ W1r,
                            const float* __restrict__ W2l, const float* __restrict__ W2r,
                            const float* __restrict__ W3l, const float* __restrict__ W3r,
                            bf16_t* __restrict__ Wb1, bf16_t* __restrict__ Wb2,
                            bf16_t* __restrict__ Wb3,
                            int* __restrict__ degi, float* __restrict__ stats)
{
    const int NW1 = 128 * IN_DIMC;
    const int NW2 = 128 * HIDC;
    const int NS  = 3 * NREP * 256;
    int j = blockIdx.x * blockDim.x + threadIdx.x;
    if (j < 2 * NW1) { Wb1[j] = (bf16_t)((j < NW1) ? W1l[j] : W1r[j - NW1]); return; }
    j -= 2 * NW1;
    if (j < 2 * NW2) { Wb2[j] = (bf16_t)((j < NW2) ? W2l[j] : W2r[j - NW2]); return; }
    j -= 2 * NW2;
    if (j < 2 * NW2) { Wb3[j] = (bf16_t)((j < NW2) ? W3l[j] : W3r[j - NW2]); return; }
    j -= 2 * NW2;
    if (j < NS) { stats[j] = 0.0f; return; }
    j -= NS;
    if (j < N_NODESC) degi[j] = 0;
}

// ---------- CSR build ----------
__global__ void degi_kernel(const int* __restrict__ ei, int* __restrict__ degi) {
    int e = blockIdx.x * blockDim.x + threadIdx.x;
    if (e < N_EDGESC) atomicAdd(&degi[ei[N_EDGESC + e]], 1);
}

__global__ __launch_bounds__(256) void scan1_kernel(const int* __restrict__ degi,
                                                    int* __restrict__ local,
                                                    int* __restrict__ partials)
{
    __shared__ int tmp[256];
    const int t = threadIdx.x;
    const int i = blockIdx.x * 256 + t;
    int v = (i < N_NODESC) ? degi[i] : 0;
    tmp[t] = v;
    __syncthreads();
    for (int off = 1; off < 256; off <<= 1) {
        int u = (t >= off) ? tmp[t - off] : 0;
        __syncthreads();
        tmp[t] += u;
        __syncthreads();
    }
    if (i < N_NODESC) local[i] = tmp[t] - v;
    if (t == 255) partials[blockIdx.x] = tmp[255];
}

// scan3 with the 196-partial scan folded in (each block redundantly re-scans)
__global__ __launch_bounds__(256) void scan3_kernel(const int* __restrict__ local,
                                                    const int* __restrict__ partials,
                                                    int* __restrict__ rowptr,
                                                    int* __restrict__ cursor)
{
    __shared__ int inc[256];
    __shared__ int orig[256];
    const int t = threadIdx.x;
    int v = (t < SCAN_NB) ? partials[t] : 0;
    inc[t] = v; orig[t] = v;
    __syncthreads();
    for (int off = 1; off < 256; off <<= 1) {
        int u = (t >= off) ? inc[t - off] : 0;
        __syncthreads();
        inc[t] += u;
        __syncthreads();
    }
    const int boff = inc[blockIdx.x] - orig[blockIdx.x];
    const int i = blockIdx.x * 256 + t;
    if (i < N_NODESC) {
        int r = local[i] + boff;
        rowptr[i] = r;
        cursor[i] = r;
    }
    if (i == 0) rowptr[N_NODESC] = N_EDGESC;
}

__global__ void fill_kernel(const int* __restrict__ ei, int* __restrict__ cursor,
                            int* __restrict__ col) {
    int e = blockIdx.x * blockDim.x + threadIdx.x;
    if (e >= N_EDGESC) return;
    int d = ei[N_EDGESC + e];
    int pos = atomicAdd(&cursor[d], 1);
    col[pos] = ei[e];
}

// ---------- fused CSR-gather mean-agg + bias + Pr + BN partial sums ----------
// ONE ROW PER WAVE (4 waves/block): serial latency chain per wave is a single
// ceil(deg/8) round vs 4 rows back-to-back. bf16x2 lanes cover 128 channels.
// NO device-scope fences (R8 lesson: ~250us/layer on 8-XCD CDNA).
__global__ __launch_bounds__(256) void agg_combine_kernel(const int* __restrict__ rowptr,
                                                          const int* __restrict__ col,
                                                          const bf16_t* __restrict__ Plb,
                                                          const bf16_t* __restrict__ Prb,
                                                          const float* __restrict__ bias,
                                                          bf16_t* __restrict__ Hb,
                                                          float* __restrict__ stats, int M)
{
    const int lane = threadIdx.x & 63;
    const int wv   = threadIdx.x >> 6;
    const int c0   = lane * 2;
    const int n    = blockIdx.x * 4 + wv;
    if (n >= M) return;

    int lo = rowptr[n], hi = rowptr[n + 1];
    float a0 = 0.f, a1 = 0.f;
    for (int e = lo; e < hi; e += 8) {
        int rem = hi - e;
        int idx[8];
#pragma unroll
        for (int j = 0; j < 8; j++) {
            int ee = e + j; if (ee > hi - 1) ee = hi - 1;
            idx[j] = col[ee];                 // broadcast loads
        }
        bf16x2 v[8];
#pragma unroll
        for (int j = 0; j < 8; j++)
            v[j] = *(const bf16x2*)&Plb[(size_t)idx[j] * HIDC + c0];  // 8 in flight
#pragma unroll
        for (int j = 0; j < 8; j++)
            if (j < rem) { a0 += (float)v[j][0]; a1 += (float)v[j][1]; }
    }
    int d = hi - lo;
    float inv = 1.0f / (float)(d > 0 ? d : 1);
    bf16x2 pr = *(const bf16x2*)&Prb[(size_t)n * HIDC + c0];
    float pre0 = fmaf(a0, inv, bias[c0]) + (float)pr[0];
    float pre1 = fmaf(a1, inv, bias[c0 + 1]) + (float)pr[1];
    bf16x2 hv; hv[0] = (bf16_t)pre0; hv[1] = (bf16_t)pre1;
    *(bf16x2*)&Hb[(size_t)n * HIDC + c0] = hv;

    const int rep = n & (NREP - 1);
    atomicAdd(&stats[rep * 256 + c0], pre0);
    atomicAdd(&stats[rep * 256 + c0 + 1], pre1);
    atomicAdd(&stats[rep * 256 + HIDC + c0], pre0 * pre0);
    atomicAdd(&stats[rep * 256 + HIDC + c0 + 1], pre1 * pre1);
}

// ---------- fused BN3-finalize + pool + linear head ----------
__global__ __launch_bounds__(128) void poolhead_kernel(const bf16_t* __restrict__ Hb,
                                                       const float* __restrict__ stats,
                                                       const float* __restrict__ g,
                                                       const float* __restrict__ be,
                                                       const int* __restrict__ batch,
                                                       const float* __restrict__ Wlin,
                                                       const float* __restrict__ blin,
                                                       float* __restrict__ out, int M)
{
    __shared__ float sp[HIDC];
    int gph = blockIdx.x;
    int c   = threadIdx.x;
    float sum = 0.f, sumsq = 0.f;
    for (int r = 0; r < NREP; r++) {
        sum   += stats[r * 256 + c];
        sumsq += stats[r * 256 + HIDC + c];
    }
    float invM = 1.0f / (float)M;
    float mean = sum * invM;
    float var  = sumsq * invM - mean * mean;
    float s = rsqrtf(var + BN_EPSC) * g[c];
    float h = be[c] - mean * s;

    int lo = 0, hi = M;
    while (lo < hi) { int m = (lo + hi) >> 1; if (batch[m] < gph) lo = m + 1; else hi = m; }
    int lo2 = lo, hi2 = M;
    while (lo2 < hi2) { int m = (lo2 + hi2) >> 1; if (batch[m] < gph + 1) lo2 = m + 1; else hi2 = m; }
    float mx = -INFINITY;
    for (int rr = lo; rr < lo2; rr++)
        mx = fmaxf(mx, fmaf((float)Hb[(size_t)rr * HIDC + c], s, h));
    sp[c] = mx;
    __syncthreads();
    if (c < NCLSC) {
        float acc = blin[c];
        for (int k = 0; k < HIDC; k++) acc += sp[k] * Wlin[c * HIDC + k];
        out[gph * NCLSC + c] = acc;
    }
}

extern "C" void kernel_launch(void* const* d_in, const int* in_sizes, int n_in,
                              void* d_out, int out_size, void* d_ws, size_t ws_size,
                              hipStream_t stream)
{
    const float* x     = (const float*)d_in[0];
    const int*   ei    = (const int*)d_in[1];
    const int*   batch = (const int*)d_in[2];
    const float* W1l = (const float*)d_in[3];
    const float* b1  = (const float*)d_in[4];
    const float* W1r = (const float*)d_in[5];
    const float* g1  = (const float*)d_in[6];
    const float* be1 = (const float*)d_in[7];
    const float* W2l = (const float*)d_in[8];
    const float* b2  = (const float*)d_in[9];
    const float* W2r = (const float*)d_in[10];
    const float* g2  = (const float*)d_in[11];
    const float* be2 = (const float*)d_in[12];
    const float* W3l = (const float*)d_in[13];
    const float* b3  = (const float*)d_in[14];
    const float* W3r = (const float*)d_in[15];
    const float* g3  = (const float*)d_in[16];
    const float* be3 = (const float*)d_in[17];
    const float* Wlin = (const float*)d_in[18];
    const float* blin = (const float*)d_in[19];

    const int M = N_NODESC;

    // workspace carve (16B aligned)
    char* w = (char*)d_ws;
    bf16_t* Plb  = (bf16_t*)w;  w += (size_t)M * HIDC * 2;
    bf16_t* Prb  = (bf16_t*)w;  w += (size_t)M * HIDC * 2;
    bf16_t* Hb   = (bf16_t*)w;  w += (size_t)M * HIDC * 2;
    bf16_t* Wb1  = (bf16_t*)w;  w += (size_t)256 * IN_DIMC * 2;
    bf16_t* Wb2  = (bf16_t*)w;  w += (size_t)256 * HIDC * 2;
    bf16_t* Wb3  = (bf16_t*)w;  w += (size_t)256 * HIDC * 2;
    int*   rowptr= (int*)w;     w += (size_t)(M + 16) * 4;
    int*   col   = (int*)w;     w += (size_t)N_EDGESC * 4;
    int*   cursor= (int*)w;     w += (size_t)M * 4;
    int*   degi  = (int*)w;     w += (size_t)M * 4;
    int*   slocal= (int*)w;     w += (size_t)M * 4;
    int*   spart = (int*)w;     w += 256 * 4;
    float* stats = (float*)w;   w += (size_t)3 * NREP * 256 * 4;   // zeroed in init

    float* stats1 = stats;
    float* stats2 = stats + NREP * 256;
    float* stats3 = stats + 2 * NREP * 256;

    const dim3 gemm_grid((M + 127) / 128, 2);
    const int agg_blocks = (M + 3) / 4;
    const int init_total = 2 * 128 * IN_DIMC + 4 * 128 * HIDC + 3 * NREP * 256 + M;

    // ---- init (weights + zeros, one dispatch) ----
    init_kernel<<<(init_total + 255) / 256, 256, 0, stream>>>(W1l, W1r, W2l, W2r, W3l, W3r,
                                                              Wb1, Wb2, Wb3, degi, stats);
    // ---- CSR build ----
    degi_kernel<<<(N_EDGESC + 255) / 256, 256, 0, stream>>>(ei, degi);
    scan1_kernel<<<SCAN_NB, 256, 0, stream>>>(degi, slocal, spart);
    scan3_kernel<<<SCAN_NB, 256, 0, stream>>>(slocal, spart, rowptr, cursor);
    fill_kernel<<<(N_EDGESC + 255) / 256, 256, 0, stream>>>(ei, cursor, col);

    // ---- layer 1 (K=768, A=x fp32; B from L2 to regs) ----
    gemm1_kernel<<<gemm_grid, 256, 0, stream>>>(x, Wb1, Plb, Prb, M);
    agg_combine_kernel<<<agg_blocks, 256, 0, stream>>>(rowptr, col, Plb, Prb, b1, Hb, stats1, M);

    // ---- layer 2 (K=128; BN1 finalize + BN1+ReLU fused; full-panel stage) ----
    gemm23_kernel<<<gemm_grid, 256, 0, stream>>>(Hb, Wb2, stats1, g1, be1, Plb, Prb, M);
    agg_combine_kernel<<<agg_blocks, 256, 0, stream>>>(rowptr, col, Plb, Prb, b2, Hb, stats2, M);

    // ---- layer 3 (K=128; BN2 finalize + BN2+ReLU fused) ----
    gemm23_kernel<<<gemm_grid, 256, 0, stream>>>(Hb, Wb3, stats2, g2, be2, Plb, Prb, M);
    agg_combine_kernel<<<agg_blocks, 256, 0, stream>>>(rowptr, col, Plb, Prb, b3, Hb, stats3, M);

    // ---- BN3 finalize + pool + head ----
    poolhead_kernel<<<N_GRAPHSC, 128, 0, stream>>>(Hb, stats3, g3, be3, batch, Wlin, blin,
                                                   (float*)d_out, M);
}